// Round 2
// baseline (2859.928 us; speedup 1.0000x reference)
//
#include <hip/hip_runtime.h>
#include <hip/hip_bf16.h>
#include <math.h>

// Problem constants
#define BB 2
#define SQ 2048
#define NH 8
#define DKH 64
#define DVH 192
#define CIN 1536    // NH*DVH
#define KPD 512     // NH*DKH
#define RLEN 4095   // 2*SQ-1

// ---------------------------------------------------------------------------
// Suffix sums of Wr: SUF0[j][o] = sum_{i>=j} Wr[i][o] (i<96), SUF1 for rows 96..191
// ---------------------------------------------------------------------------
__global__ void suffix_kernel(const float* __restrict__ Wr,
                              float* __restrict__ SUF0, float* __restrict__ SUF1) {
    int o = blockIdx.x * 256 + threadIdx.x;
    if (o >= KPD) return;
    float s = 0.f;
    SUF0[96 * KPD + o] = 0.f;
    for (int j = 95; j >= 0; j--) { s += Wr[j * KPD + o]; SUF0[j * KPD + o] = s; }
    s = 0.f;
    SUF1[96 * KPD + o] = 0.f;
    for (int j = 95; j >= 0; j--) { s += Wr[(96 + j) * KPD + o]; SUF1[j * KPD + o] = s; }
}

// ---------------------------------------------------------------------------
// r_k[h, p, e] = SUF0[jmin(p)][h*64+e] + sign(pos)*SUF1[jmin(p)][h*64+e]
// ---------------------------------------------------------------------------
__global__ void rk_kernel(const float* __restrict__ SUF0, const float* __restrict__ SUF1,
                          float* __restrict__ RK) {
    int p = blockIdx.x;             // 0..4094
    int tid = threadIdx.x;
    __shared__ float cwv[96];
    __shared__ int jmin_s;
    double pr_d = exp(log((double)(SQ + 1)) / 96.0);
    if (tid < 96) cwv[tid] = (float)(pow(pr_d, (double)(tid + 1)) - 1.0);
    __syncthreads();
    float pos = (float)(p - (SQ - 1));
    float apos = fabsf(pos);
    float sgn = (pos > 0.f) ? 1.f : ((pos < 0.f) ? -1.f : 0.f);
    if (tid == 0) {
        int jm = 0;
        for (int j = 0; j < 96; j++) jm += (cwv[j] <= apos) ? 1 : 0;
        jmin_s = jm;
    }
    __syncthreads();
    int jm = jmin_s;
    for (int o = tid; o < KPD; o += 256) {
        float v = SUF0[jm * KPD + o] + sgn * SUF1[jm * KPD + o];
        int h = o >> 6, e = o & 63;
        RK[(size_t)h * (RLEN * DKH) + (size_t)p * DKH + e] = v;
    }
}

// ---------------------------------------------------------------------------
// Generic 128x128 fp32 GEMM tile core.
// ---------------------------------------------------------------------------
__device__ __forceinline__ void gemm_core(
    const float* __restrict__ Ab, const float* __restrict__ Wb, float* __restrict__ Ob,
    int Kdim, int lda, int ldw, int ldo, float scale, const float* __restrict__ bias,
    float* __restrict__ As, float* __restrict__ Bs) {
    const int tid = threadIdx.x;
    const int tx = tid & 15, ty = tid >> 4;
    float acc[8][8];
#pragma unroll
    for (int i = 0; i < 8; i++)
#pragma unroll
        for (int j = 0; j < 8; j++) acc[i][j] = 0.f;

    const int am = tid >> 1, ak = (tid & 1) * 4;
    const int bk = tid >> 5, bn = (tid & 31) * 4;

    for (int k0 = 0; k0 < Kdim; k0 += 8) {
        float4 a4 = *(const float4*)(Ab + (size_t)am * lda + k0 + ak);
        float4 b4 = *(const float4*)(Wb + (size_t)(k0 + bk) * ldw + bn);
        __syncthreads();
        As[(ak + 0) * 128 + am] = a4.x;
        As[(ak + 1) * 128 + am] = a4.y;
        As[(ak + 2) * 128 + am] = a4.z;
        As[(ak + 3) * 128 + am] = a4.w;
        *(float4*)(Bs + bk * 128 + bn) = b4;
        __syncthreads();
#pragma unroll
        for (int kk = 0; kk < 8; kk++) {
            float a[8], bb[8];
            *(float4*)(a)      = *(const float4*)(As + kk * 128 + ty * 8);
            *(float4*)(a + 4)  = *(const float4*)(As + kk * 128 + ty * 8 + 4);
            *(float4*)(bb)     = *(const float4*)(Bs + kk * 128 + tx * 8);
            *(float4*)(bb + 4) = *(const float4*)(Bs + kk * 128 + tx * 8 + 4);
#pragma unroll
            for (int i = 0; i < 8; i++)
#pragma unroll
                for (int j = 0; j < 8; j++)
                    acc[i][j] = fmaf(a[i], bb[j], acc[i][j]);
        }
    }
#pragma unroll
    for (int i = 0; i < 8; i++) {
        int row = ty * 8 + i;
        float o[8];
#pragma unroll
        for (int j = 0; j < 8; j++) {
            float v = acc[i][j] * scale;
            if (bias) v += bias[tx * 8 + j];
            o[j] = v;
        }
        *(float4*)(Ob + (size_t)row * ldo + tx * 8)     = *(float4*)(o);
        *(float4*)(Ob + (size_t)row * ldo + tx * 8 + 4) = *(float4*)(o + 4);
    }
}

// Fused QKV projection: grid (20, 32). Block-cols 0..3 -> Q (scaled), 4..7 -> K, 8..19 -> V.
__global__ __launch_bounds__(256) void qkv_gemm(
    const float* __restrict__ x, const float* __restrict__ Wq, const float* __restrict__ Wk,
    const float* __restrict__ Wv, float* __restrict__ Q, float* __restrict__ Kb,
    float* __restrict__ V) {
    __shared__ float As[8 * 128];
    __shared__ float Bs[8 * 128];
    int bc = blockIdx.x;
    int m0 = blockIdx.y * 128;
    const float* W;
    float* outp;
    int ldw, n0;
    float scale = 1.f;
    if (bc < 4)      { W = Wq; outp = Q;  ldw = KPD; n0 = bc * 128;       scale = 0.125f; }
    else if (bc < 8) { W = Wk; outp = Kb; ldw = KPD; n0 = (bc - 4) * 128; }
    else             { W = Wv; outp = V;  ldw = CIN; n0 = (bc - 8) * 128; }
    gemm_core(x + (size_t)m0 * CIN, W + n0, outp + (size_t)m0 * ldw + n0,
              CIN, CIN, ldw, ldw, scale, nullptr, As, Bs);
}

// Output projection: out = ATT @ We + be. grid (12, 32).
__global__ __launch_bounds__(256) void out_gemm(
    const float* __restrict__ ATT, const float* __restrict__ We,
    const float* __restrict__ be, float* __restrict__ out) {
    __shared__ float As[8 * 128];
    __shared__ float Bs[8 * 128];
    int n0 = blockIdx.x * 128;
    int m0 = blockIdx.y * 128;
    gemm_core(ATT + (size_t)m0 * CIN, We + n0, out + (size_t)m0 * CIN + n0,
              CIN, CIN, CIN, CIN, 1.f, be + n0, As, Bs);
}

// cK[(b*8+h)*2048 + k] = rwb[h,:] . K[b,k,h,:]
__global__ void ck_kernel(const float* __restrict__ Kb, const float* __restrict__ rwb,
                          float* __restrict__ cK) {
    int g = blockIdx.x * 256 + threadIdx.x;  // < 32768
    int k = g & 2047, h = (g >> 11) & 7, b = g >> 14;
    const float4* kp = (const float4*)(Kb + ((size_t)(b * SQ + k)) * KPD + h * DKH);
    const float4* wp = (const float4*)(rwb + h * DKH);
    float s = 0.f;
#pragma unroll
    for (int d = 0; d < 16; d++) {
        float4 kv = kp[d], wv = wp[d];
        s += kv.x * wv.x + kv.y * wv.y + kv.z * wv.z + kv.w * wv.w;
    }
    cK[g] = s;
}

// cR[h*4095 + d] = rrb[h,:] . RK[h,d,:]
__global__ void cr_kernel(const float* __restrict__ RK, const float* __restrict__ rrb,
                          float* __restrict__ cR) {
    int g = blockIdx.x * 256 + threadIdx.x;
    if (g >= NH * RLEN) return;
    int h = g / RLEN, d = g - h * RLEN;
    const float4* rp = (const float4*)(RK + (size_t)h * (RLEN * DKH) + (size_t)d * DKH);
    const float4* wp = (const float4*)(rrb + h * DKH);
    float s = 0.f;
#pragma unroll
    for (int d4 = 0; d4 < 16; d4++) {
        float4 rv = rp[d4], wv = wp[d4];
        s += rv.x * wv.x + rv.y * wv.y + rv.z * wv.z + rv.w * wv.w;
    }
    cR[g] = s;
}

// ---------------------------------------------------------------------------
// Flash-style relative attention.
// logits[q,k] = q.k + q.rk[d] + cK[h,k] + cR[h,d],  d = k - q + 2047
// grid (S/32, H, B), 256 threads. Thread (r=tid>>3, c=tid&7): row r, 4 score
// cols c+8i, and PV dv-chunk [c*24, c*24+24).
// ---------------------------------------------------------------------------
__global__ __launch_bounds__(256) void attn_kernel(
    const float* __restrict__ Q, const float* __restrict__ Kb, const float* __restrict__ V,
    const float* __restrict__ RK, const float* __restrict__ cK, const float* __restrict__ cR,
    float* __restrict__ ATT) {
    __shared__ float k_s[32][68];   // padded: conflict-free column reads
    __shared__ float rk_s[63][68];
    __shared__ float v_s[32][192];

    const int q0 = blockIdx.x * 32;
    const int h = blockIdx.y, b = blockIdx.z;
    const int tid = threadIdx.x;
    const int r = tid >> 3, c = tid & 7;

    // q row (scaled already) into registers: 64 floats
    float4 qreg[16];
    const float* qrow = Q + ((size_t)(b * SQ + q0 + r)) * KPD + h * DKH;
#pragma unroll
    for (int i = 0; i < 16; i++) qreg[i] = *(const float4*)(qrow + i * 4);

    float acc[24];
#pragma unroll
    for (int j = 0; j < 24; j++) acc[j] = 0.f;
    float mrun = -INFINITY, lrun = 0.f;

    const float* cKbase = cK + (size_t)(b * NH + h) * SQ;
    const float* cRbase = cR + (size_t)h * RLEN;
    const float* RKbase = RK + (size_t)h * (RLEN * DKH);

    for (int kt = 0; kt < SQ / 32; kt++) {
        const int k0 = kt * 32;
        const int d0 = k0 - q0 + 2016;  // rk_s row dd corresponds to global d = d0+dd

        // ---- stage K tile (32x64) ----
        {
            int idx = tid * 8, kk = idx >> 6, e = idx & 63;
            const float* src = Kb + ((size_t)(b * SQ + k0 + kk)) * KPD + h * DKH + e;
            *(float4*)&k_s[kk][e]     = *(const float4*)(src);
            *(float4*)&k_s[kk][e + 4] = *(const float4*)(src + 4);
        }
        // ---- stage V tile (32x192) ----
#pragma unroll
        for (int i = 0; i < 6; i++) {
            int f4 = tid + i * 256;            // 0..1535 float4s
            int kk = f4 / 48, dv = (f4 % 48) * 4;
            *(float4*)&v_s[kk][dv] =
                *(const float4*)(V + ((size_t)(b * SQ + k0 + kk)) * CIN + h * DVH + dv);
        }
        // ---- stage RK tile (63x64) ----
#pragma unroll
        for (int i = 0; i < 4; i++) {
            int f4 = tid + i * 256;            // need 1008 float4s
            if (f4 < 1008) {
                int dd = f4 >> 4, e = (f4 & 15) * 4;
                *(float4*)&rk_s[dd][e] = *(const float4*)(RKbase + (size_t)(d0 + dd) * DKH + e);
            }
        }
        __syncthreads();

        // ---- scores ----
        float p[4];
        float tmax = -INFINITY;
#pragma unroll
        for (int i = 0; i < 4; i++) {
            int col = c + 8 * i;
            int dd = col + 31 - r;
            float s1 = 0.f, s2 = 0.f;
#pragma unroll
            for (int d4 = 0; d4 < 16; d4++) {
                float4 qv = qreg[d4];
                float4 kv = *(const float4*)&k_s[col][d4 * 4];
                float4 rv = *(const float4*)&rk_s[dd][d4 * 4];
                s1 = fmaf(qv.x, kv.x, fmaf(qv.y, kv.y, fmaf(qv.z, kv.z, fmaf(qv.w, kv.w, s1))));
                s2 = fmaf(qv.x, rv.x, fmaf(qv.y, rv.y, fmaf(qv.z, rv.z, fmaf(qv.w, rv.w, s2))));
            }
            float s = s1 + s2 + cKbase[k0 + col] + cRbase[d0 + dd];
            p[i] = s;
            tmax = fmaxf(tmax, s);
        }
        // row reduction across the 8 c-lanes (consecutive within wave)
        tmax = fmaxf(tmax, __shfl_xor(tmax, 1));
        tmax = fmaxf(tmax, __shfl_xor(tmax, 2));
        tmax = fmaxf(tmax, __shfl_xor(tmax, 4));
        float newm = fmaxf(mrun, tmax);
        float scl = expf(mrun - newm);  // -inf -> 0 on first tile
        float lsum = 0.f;
#pragma unroll
        for (int i = 0; i < 4; i++) { p[i] = expf(p[i] - newm); lsum += p[i]; }
        lsum += __shfl_xor(lsum, 1);
        lsum += __shfl_xor(lsum, 2);
        lsum += __shfl_xor(lsum, 4);
        lrun = lrun * scl + lsum;
        mrun = newm;
#pragma unroll
        for (int j = 0; j < 24; j++) acc[j] *= scl;

        // ---- PV: acc[dv] += p[k] * v[k][dv] ----
        const int lanebase = ((tid & 63) >> 3) << 3;  // wave-local row base lane
#pragma unroll
        for (int k = 0; k < 32; k++) {
            float w = __shfl(p[k >> 3], lanebase + (k & 7), 64);
            const float* vr = &v_s[k][c * 24];
#pragma unroll
            for (int j4 = 0; j4 < 6; j4++) {
                float4 vv = *(const float4*)(vr + j4 * 4);
                acc[j4 * 4 + 0] = fmaf(w, vv.x, acc[j4 * 4 + 0]);
                acc[j4 * 4 + 1] = fmaf(w, vv.y, acc[j4 * 4 + 1]);
                acc[j4 * 4 + 2] = fmaf(w, vv.z, acc[j4 * 4 + 2]);
                acc[j4 * 4 + 3] = fmaf(w, vv.w, acc[j4 * 4 + 3]);
            }
        }
        __syncthreads();
    }

    float inv = 1.f / lrun;
    float* orow = ATT + ((size_t)(b * SQ + q0 + r)) * CIN + h * DVH + c * 24;
#pragma unroll
    for (int j4 = 0; j4 < 6; j4++) {
        float4 o;
        o.x = acc[j4 * 4 + 0] * inv;
        o.y = acc[j4 * 4 + 1] * inv;
        o.z = acc[j4 * 4 + 2] * inv;
        o.w = acc[j4 * 4 + 3] * inv;
        *(float4*)(orow + j4 * 4) = o;
    }
}

// ---------------------------------------------------------------------------
extern "C" void kernel_launch(void* const* d_in, const int* in_sizes, int n_in,
                              void* d_out, int out_size, void* d_ws, size_t ws_size,
                              hipStream_t stream) {
    const float* x   = (const float*)d_in[0];
    const float* Wq  = (const float*)d_in[1];
    const float* Wk  = (const float*)d_in[2];
    const float* Wv  = (const float*)d_in[3];
    const float* Wr  = (const float*)d_in[4];
    const float* rwb = (const float*)d_in[5];
    const float* rrb = (const float*)d_in[6];
    const float* We  = (const float*)d_in[7];
    const float* be  = (const float*)d_in[8];
    float* out = (float*)d_out;

    float* ws = (float*)d_ws;
    float* Q    = ws;                       // 4096*512
    float* Kb   = Q + 2097152;              // 4096*512
    float* V    = Kb + 2097152;             // 4096*1536
    float* RK   = V + 6291456;              // 8*4095*64
    float* SUF0 = RK + 2096640;             // 97*512
    float* SUF1 = SUF0 + 49664;             // 97*512
    float* cKb  = SUF1 + 49664;             // 2*8*2048
    float* cRb  = cKb + 32768;              // 8*4095
    float* ATT  = cRb + 32760;              // 4096*1536

    suffix_kernel<<<2, 256, 0, stream>>>(Wr, SUF0, SUF1);
    rk_kernel<<<RLEN, 256, 0, stream>>>(SUF0, SUF1, RK);
    qkv_gemm<<<dim3(20, 32), 256, 0, stream>>>(x, Wq, Wk, Wv, Q, Kb, V);
    ck_kernel<<<128, 256, 0, stream>>>(Kb, rwb, cKb);
    cr_kernel<<<128, 256, 0, stream>>>(RK, rrb, cRb);
    attn_kernel<<<dim3(SQ / 32, NH, BB), 256, 0, stream>>>(Q, Kb, V, RK, cKb, cRb, ATT);
    out_gemm<<<dim3(12, 32), 256, 0, stream>>>(ATT, We, be, out);
}

// Round 4
// 1049.826 us; speedup vs baseline: 2.7242x; 2.7242x over previous
//
#include <hip/hip_runtime.h>
#include <hip/hip_bf16.h>
#include <math.h>

// Problem constants
#define BB 2
#define SQ 2048
#define NH 8
#define DKH 64
#define DVH 192
#define CIN 1536    // NH*DVH
#define KPD 512     // NH*DKH

typedef unsigned short u16t;
typedef short bf16x8 __attribute__((ext_vector_type(8)));
typedef float f32x4 __attribute__((ext_vector_type(4)));

__device__ __forceinline__ u16t f2bf(float f) {
    unsigned int x = __float_as_uint(f);
    unsigned int r = x + 0x7FFF + ((x >> 16) & 1);   // RNE
    return (u16t)(r >> 16);
}
__device__ __forceinline__ float bf2f(u16t u) {
    return __uint_as_float(((unsigned int)u) << 16);
}

// ---------------------------------------------------------------------------
// Suffix sums of Wr: SUF0[j][o] = sum_{i>=j} Wr[i][o] (i<96), SUF1 rows 96..191
// ---------------------------------------------------------------------------
__global__ void suffix_kernel(const float* __restrict__ Wr,
                              float* __restrict__ SUF0, float* __restrict__ SUF1) {
    int o = blockIdx.x * 256 + threadIdx.x;
    if (o >= KPD) return;
    float s = 0.f;
    SUF0[96 * KPD + o] = 0.f;
    for (int j = 95; j >= 0; j--) { s += Wr[j * KPD + o]; SUF0[j * KPD + o] = s; }
    s = 0.f;
    SUF1[96 * KPD + o] = 0.f;
    for (int j = 95; j >= 0; j--) { s += Wr[(96 + j) * KPD + o]; SUF1[j * KPD + o] = s; }
}

// jmt[dist] = #{j : cw[j] <= dist}, exact same fp32 comparison as reference
__global__ void jmt_kernel(unsigned char* __restrict__ jmt) {
    int tid = threadIdx.x;
    __shared__ float cwv[96];
    double pr_d = exp(log((double)(SQ + 1)) / 96.0);
    if (tid < 96) cwv[tid] = (float)(pow(pr_d, (double)(tid + 1)) - 1.0);
    __syncthreads();
    for (int dist = tid; dist < SQ; dist += 256) {
        float ad = (float)dist;
        int jm = 0;
        for (int j = 0; j < 96; j++) jm += (cwv[j] <= ad) ? 1 : 0;
        jmt[dist] = (unsigned char)jm;
    }
}

// ---------------------------------------------------------------------------
// A01[b,h,q][j] = pack(bf16((q_s+rrb).suf1[j]), bf16((q_s+rrb).suf0[j]))
// ---------------------------------------------------------------------------
__global__ __launch_bounds__(256) void a01_kernel(
    const float* __restrict__ Q, const float* __restrict__ SUF0,
    const float* __restrict__ SUF1, const float* __restrict__ rrb,
    unsigned int* __restrict__ A01) {
    __shared__ float s0[97][65];
    __shared__ float s1[97][65];
    __shared__ float qs[32][65];
    int h = blockIdx.y, b = blockIdx.z, qb = blockIdx.x * 32;
    int tid = threadIdx.x;
    for (int idx = tid; idx < 97 * 64; idx += 256) {
        int j = idx >> 6, e = idx & 63;
        s0[j][e] = SUF0[j * KPD + h * 64 + e];
        s1[j][e] = SUF1[j * KPD + h * 64 + e];
    }
    for (int idx = tid; idx < 32 * 64; idx += 256) {
        int q = idx >> 6, e = idx & 63;
        qs[q][e] = Q[((size_t)(b * SQ + qb + q)) * KPD + h * 64 + e] + rrb[h * 64 + e];
    }
    __syncthreads();
    int q = tid >> 3, part = tid & 7;
    for (int j = part; j < 97; j += 8) {
        float d0 = 0.f, d1 = 0.f;
        for (int e = 0; e < 64; e++) {
            float qv = qs[q][e];
            d0 += qv * s0[j][e];
            d1 += qv * s1[j][e];
        }
        unsigned int pk = ((unsigned int)f2bf(d1) << 16) | (unsigned int)f2bf(d0);
        A01[(((size_t)(b * NH + h)) * SQ + qb + q) * 97 + j] = pk;
    }
}

// ---------------------------------------------------------------------------
// fp32 GEMM tile core (accumulate only)
// ---------------------------------------------------------------------------
__device__ __forceinline__ void gemm_acc(
    const float* __restrict__ Ab, const float* __restrict__ Wb,
    int Kdim, int lda, int ldw, float (&acc)[8][8],
    float* __restrict__ As, float* __restrict__ Bs) {
    const int tid = threadIdx.x;
    const int tx = tid & 15, ty = tid >> 4;
#pragma unroll
    for (int i = 0; i < 8; i++)
#pragma unroll
        for (int j = 0; j < 8; j++) acc[i][j] = 0.f;

    const int am = tid >> 1, ak = (tid & 1) * 4;
    const int bk = tid >> 5, bn = (tid & 31) * 4;

    for (int k0 = 0; k0 < Kdim; k0 += 8) {
        float4 a4 = *(const float4*)(Ab + (size_t)am * lda + k0 + ak);
        float4 b4 = *(const float4*)(Wb + (size_t)(k0 + bk) * ldw + bn);
        __syncthreads();
        As[(ak + 0) * 128 + am] = a4.x;
        As[(ak + 1) * 128 + am] = a4.y;
        As[(ak + 2) * 128 + am] = a4.z;
        As[(ak + 3) * 128 + am] = a4.w;
        *(float4*)(Bs + bk * 128 + bn) = b4;
        __syncthreads();
#pragma unroll
        for (int kk = 0; kk < 8; kk++) {
            float a[8], bb[8];
            *(float4*)(a)      = *(const float4*)(As + kk * 128 + ty * 8);
            *(float4*)(a + 4)  = *(const float4*)(As + kk * 128 + ty * 8 + 4);
            *(float4*)(bb)     = *(const float4*)(Bs + kk * 128 + tx * 8);
            *(float4*)(bb + 4) = *(const float4*)(Bs + kk * 128 + tx * 8 + 4);
#pragma unroll
            for (int i = 0; i < 8; i++)
#pragma unroll
                for (int j = 0; j < 8; j++)
                    acc[i][j] = fmaf(a[i], bb[j], acc[i][j]);
        }
    }
}

// Fused QKV projection. grid (20, 32). bc 0..3 -> Q (f32, scaled); 4..7 -> K (bf16);
// 8..19 -> V written TRANSPOSED as bf16 VT[b,h,dv,s].
__global__ __launch_bounds__(256) void qkv_gemm(
    const float* __restrict__ x, const float* __restrict__ Wq, const float* __restrict__ Wk,
    const float* __restrict__ Wv, float* __restrict__ Q, u16t* __restrict__ Kbf,
    u16t* __restrict__ VT) {
    __shared__ float As[8 * 128];
    __shared__ float Bs[8 * 128];
    int bc = blockIdx.x;
    int m0 = blockIdx.y * 128;
    const int tid = threadIdx.x;
    const int tx = tid & 15, ty = tid >> 4;
    float acc[8][8];

    if (bc < 4) {
        int n0 = bc * 128;
        gemm_acc(x + (size_t)m0 * CIN, Wq + n0, CIN, CIN, KPD, acc, As, Bs);
#pragma unroll
        for (int i = 0; i < 8; i++) {
            int row = m0 + ty * 8 + i;
            float o[8];
#pragma unroll
            for (int j = 0; j < 8; j++) o[j] = acc[i][j] * 0.125f;
            *(float4*)(Q + (size_t)row * KPD + n0 + tx * 8)     = *(float4*)(o);
            *(float4*)(Q + (size_t)row * KPD + n0 + tx * 8 + 4) = *(float4*)(o + 4);
        }
    } else if (bc < 8) {
        int n0 = (bc - 4) * 128;
        gemm_acc(x + (size_t)m0 * CIN, Wk + n0, CIN, CIN, KPD, acc, As, Bs);
#pragma unroll
        for (int i = 0; i < 8; i++) {
            int row = m0 + ty * 8 + i;
            bf16x8 v;
#pragma unroll
            for (int j = 0; j < 8; j++) v[j] = (short)f2bf(acc[i][j]);
            *(bf16x8*)&Kbf[(size_t)row * KPD + n0 + tx * 8] = v;
        }
    } else {
        int n0 = (bc - 8) * 128;
        gemm_acc(x + (size_t)m0 * CIN, Wv + n0, CIN, CIN, CIN, acc, As, Bs);
        int m = m0 + ty * 8;            // 8 consecutive rows, same batch
        int b = m >> 11, s = m & 2047;
#pragma unroll
        for (int j = 0; j < 8; j++) {
            int col = n0 + tx * 8 + j;
            int h = col / 192, dv = col - h * 192;
            bf16x8 v;
#pragma unroll
            for (int i = 0; i < 8; i++) v[i] = (short)f2bf(acc[i][j]);
            *(bf16x8*)&VT[(((size_t)(b * NH + h)) * 192 + dv) * SQ + s] = v;
        }
    }
}

// Output projection: out = ATT @ We + be. grid (12, 32).
__global__ __launch_bounds__(256) void out_gemm(
    const float* __restrict__ ATT, const float* __restrict__ We,
    const float* __restrict__ be, float* __restrict__ out) {
    __shared__ float As[8 * 128];
    __shared__ float Bs[8 * 128];
    int n0 = blockIdx.x * 128;
    int m0 = blockIdx.y * 128;
    const int tid = threadIdx.x;
    const int tx = tid & 15, ty = tid >> 4;
    float acc[8][8];
    gemm_acc(ATT + (size_t)m0 * CIN, We + n0, CIN, CIN, CIN, acc, As, Bs);
#pragma unroll
    for (int i = 0; i < 8; i++) {
        int row = m0 + ty * 8 + i;
        float o[8];
#pragma unroll
        for (int j = 0; j < 8; j++) o[j] = acc[i][j] + be[n0 + tx * 8 + j];
        *(float4*)(out + (size_t)row * CIN + n0 + tx * 8)     = *(float4*)(o);
        *(float4*)(out + (size_t)row * CIN + n0 + tx * 8 + 4) = *(float4*)(o + 4);
    }
}

// cK[(b*8+h)*2048 + k] = rwb[h,:] . K[b,k,h,:]
__global__ void ck_kernel(const u16t* __restrict__ Kbf, const float* __restrict__ rwb,
                          float* __restrict__ cK) {
    int g = blockIdx.x * 256 + threadIdx.x;  // < 32768
    int k = g & 2047, h = (g >> 11) & 7, b = g >> 14;
    const u16t* kp = Kbf + ((size_t)(b * SQ + k)) * KPD + h * 64;
    const float* wp = rwb + h * 64;
    float s = 0.f;
#pragma unroll
    for (int c = 0; c < 8; c++) {
        bf16x8 kv = *(const bf16x8*)(kp + c * 8);
#pragma unroll
        for (int j = 0; j < 8; j++) s += bf2f((u16t)kv[j]) * wp[c * 8 + j];
    }
    cK[g] = s;
}

// ---------------------------------------------------------------------------
// MFMA flash attention. grid (S/64, H, B), 256 thr = 4 waves; wave w owns 16 q-rows.
// KVBLK=32. logits = QK^T(mfma) + A0[q][jm]+sgn*A1[q][jm] + cK[k], jm=jmt[|k-q|].
// ---------------------------------------------------------------------------
__global__ __launch_bounds__(256) void attn_mfma(
    const float* __restrict__ Q, const u16t* __restrict__ Kbf, const u16t* __restrict__ VT,
    const unsigned int* __restrict__ A01, const unsigned char* __restrict__ jmtg,
    const float* __restrict__ cKg, float* __restrict__ ATT) {
    __shared__ __align__(16) u16t k_s[32 * 72];        // [32 k][64 d + pad8]
    __shared__ __align__(16) u16t vt_s[192 * 40];      // [192 dv][32 k + pad8]
    __shared__ __align__(16) u16t p_s[4][16 * 40];     // per-wave [16 q][32 k + pad8]
    __shared__ unsigned int a01_s[64 * 97];
    __shared__ unsigned char jmt_s[2048];
    __shared__ float ck_s[32];

    const int q0blk = blockIdx.x * 64;
    const int h = blockIdx.y, b = blockIdx.z;
    const int tid = threadIdx.x;
    const int w = tid >> 6, l = tid & 63;
    const int lan15 = l & 15, grp = l >> 4;

    // one-time stages
    ((uint2*)jmt_s)[tid] = ((const uint2*)jmtg)[tid];
    {
        const unsigned int* a01g = A01 + (((size_t)(b * NH + h)) * SQ + q0blk) * 97;
        for (int idx = tid; idx < 64 * 97; idx += 256) a01_s[idx] = a01g[idx];
    }

    // Q fragments (f32 -> bf16), rows = wave-local l&15
    const int qrow = q0blk + w * 16 + lan15;
    bf16x8 qfrag[2];
#pragma unroll
    for (int g = 0; g < 2; g++) {
        const float* qp = Q + ((size_t)(b * SQ + qrow)) * KPD + h * 64 + g * 32 + grp * 8;
        float4 qa = *(const float4*)qp, qb4 = *(const float4*)(qp + 4);
        bf16x8 f;
        f[0] = (short)f2bf(qa.x); f[1] = (short)f2bf(qa.y);
        f[2] = (short)f2bf(qa.z); f[3] = (short)f2bf(qa.w);
        f[4] = (short)f2bf(qb4.x); f[5] = (short)f2bf(qb4.y);
        f[6] = (short)f2bf(qb4.z); f[7] = (short)f2bf(qb4.w);
        qfrag[g] = f;
    }

    f32x4 o_acc[12];
#pragma unroll
    for (int c = 0; c < 12; c++) o_acc[c] = (f32x4){0.f, 0.f, 0.f, 0.f};
    float m_run[4] = {-INFINITY, -INFINITY, -INFINITY, -INFINITY};
    float l_run[4] = {0.f, 0.f, 0.f, 0.f};

    const u16t* Kbase = Kbf + ((size_t)b * SQ) * KPD + h * 64;
    const u16t* Vbase = VT + ((size_t)(b * NH + h)) * 192 * SQ;
    const float* cKb = cKg + (size_t)(b * NH + h) * SQ;
    u16t* p_ws = p_s[w];

    for (int kt = 0; kt < SQ / 32; kt++) {
        const int k0 = kt * 32;
        // ---- stage K tile: 256 chunks of 8 bf16 ----
        {
            int row = tid >> 3, g = tid & 7;
            *(bf16x8*)&k_s[row * 72 + g * 8] =
                *(const bf16x8*)(Kbase + (size_t)(k0 + row) * KPD + g * 8);
        }
        // ---- stage VT tile: 768 chunks ----
#pragma unroll
        for (int rep = 0; rep < 3; rep++) {
            int c = tid + rep * 256;
            int dv = c >> 2, g = c & 3;
            *(bf16x8*)&vt_s[dv * 40 + g * 8] =
                *(const bf16x8*)(Vbase + (size_t)dv * SQ + k0 + g * 8);
        }
        if (tid < 32) ck_s[tid] = cKb[k0 + tid];
        __syncthreads();

        // ---- S = Q K^T : 2 col-tiles x 2 kdim-frags ----
        f32x4 sacc[2];
#pragma unroll
        for (int ct = 0; ct < 2; ct++) {
            int krow = 16 * ct + lan15;
            bf16x8 kf0 = *(bf16x8*)&k_s[krow * 72 + grp * 8];
            bf16x8 kf1 = *(bf16x8*)&k_s[krow * 72 + 32 + grp * 8];
            f32x4 z = (f32x4){0.f, 0.f, 0.f, 0.f};
            z = __builtin_amdgcn_mfma_f32_16x16x32_bf16(qfrag[0], kf0, z, 0, 0, 0);
            z = __builtin_amdgcn_mfma_f32_16x16x32_bf16(qfrag[1], kf1, z, 0, 0, 0);
            sacc[ct] = z;
        }
        float ckv[2] = {ck_s[lan15], ck_s[16 + lan15]};

        // ---- epilogue + online softmax (rows: q = w*16 + grp*4 + i) ----
#pragma unroll
        for (int i = 0; i < 4; i++) {
            const int qg = q0blk + w * 16 + grp * 4 + i;
            float sv[2];
#pragma unroll
            for (int ct = 0; ct < 2; ct++) {
                int kg = k0 + 16 * ct + lan15;
                int dg = kg - qg;
                int dist = dg < 0 ? -dg : dg;
                int jm = (int)jmt_s[dist];
                unsigned int pk = a01_s[(w * 16 + grp * 4 + i) * 97 + jm];
                float a0 = bf2f((u16t)(pk & 0xFFFF));
                float a1 = bf2f((u16t)(pk >> 16));
                float sgn = (dg > 0) ? 1.f : (dg < 0 ? -1.f : 0.f);
                sv[ct] = sacc[ct][i] + a0 + sgn * a1 + ckv[ct];
            }
            float mx = fmaxf(sv[0], sv[1]);
            mx = fmaxf(mx, __shfl_xor(mx, 1));
            mx = fmaxf(mx, __shfl_xor(mx, 2));
            mx = fmaxf(mx, __shfl_xor(mx, 4));
            mx = fmaxf(mx, __shfl_xor(mx, 8));
            float mn = fmaxf(m_run[i], mx);
            float scl = __expf(m_run[i] - mn);
            float p0 = __expf(sv[0] - mn), p1 = __expf(sv[1] - mn);
            float ls = p0 + p1;
            ls += __shfl_xor(ls, 1);
            ls += __shfl_xor(ls, 2);
            ls += __shfl_xor(ls, 4);
            ls += __shfl_xor(ls, 8);
            l_run[i] = l_run[i] * scl + ls;
            m_run[i] = mn;
#pragma unroll
            for (int c = 0; c < 12; c++) o_acc[c][i] *= scl;
            p_ws[(grp * 4 + i) * 40 + lan15]      = f2bf(p0);
            p_ws[(grp * 4 + i) * 40 + 16 + lan15] = f2bf(p1);
        }

        // ---- PV: O += P V ----
        bf16x8 pa = *(bf16x8*)&p_ws[lan15 * 40 + grp * 8];
#pragma unroll
        for (int c = 0; c < 12; c++) {
            bf16x8 vf = *(bf16x8*)&vt_s[(16 * c + lan15) * 40 + grp * 8];
            o_acc[c] = __builtin_amdgcn_mfma_f32_16x16x32_bf16(pa, vf, o_acc[c], 0, 0, 0);
        }
        __syncthreads();
    }

    // ---- write ATT ----
    float inv[4];
#pragma unroll
    for (int i = 0; i < 4; i++) inv[i] = 1.f / l_run[i];
#pragma unroll
    for (int c = 0; c < 12; c++)
#pragma unroll
        for (int i = 0; i < 4; i++) {
            int qg = q0blk + w * 16 + grp * 4 + i;
            ATT[((size_t)(b * SQ + qg)) * CIN + h * 192 + 16 * c + lan15] = o_acc[c][i] * inv[i];
        }
}

// ---------------------------------------------------------------------------
extern "C" void kernel_launch(void* const* d_in, const int* in_sizes, int n_in,
                              void* d_out, int out_size, void* d_ws, size_t ws_size,
                              hipStream_t stream) {
    const float* x   = (const float*)d_in[0];
    const float* Wq  = (const float*)d_in[1];
    const float* Wk  = (const float*)d_in[2];
    const float* Wv  = (const float*)d_in[3];
    const float* Wr  = (const float*)d_in[4];
    const float* rwb = (const float*)d_in[5];
    const float* rrb = (const float*)d_in[6];
    const float* We  = (const float*)d_in[7];
    const float* be  = (const float*)d_in[8];
    float* out = (float*)d_out;

    float* ws = (float*)d_ws;
    float*        Q    = ws;                                // 2097152 f32
    u16t*         Kbf  = (u16t*)(ws + 2097152);             // 2097152 u16 = 1048576 f
    u16t*         VT   = (u16t*)(ws + 3145728);             // 6291456 u16 = 3145728 f
    float*        SUF0 = ws + 6291456;                      // 49664
    float*        SUF1 = ws + 6341120;                      // 49664
    float*        cKb  = ws + 6390784;                      // 32768
    unsigned int* A01  = (unsigned int*)(ws + 6423552);     // 3178496 u32
    unsigned char* jmt = (unsigned char*)(ws + 9602048);    // 2048 B
    float*        ATT  = ws + 9602560;                      // 6291456
    // total 15894016 floats = 63.6 MB

    suffix_kernel<<<2, 256, 0, stream>>>(Wr, SUF0, SUF1);
    jmt_kernel<<<1, 256, 0, stream>>>(jmt);
    qkv_gemm<<<dim3(20, 32), 256, 0, stream>>>(x, Wq, Wk, Wv, Q, Kbf, VT);
    ck_kernel<<<128, 256, 0, stream>>>(Kbf, rwb, cKb);
    a01_kernel<<<dim3(64, NH, BB), 256, 0, stream>>>(Q, SUF0, SUF1, rrb, A01);
    attn_mfma<<<dim3(SQ / 64, NH, BB), 256, 0, stream>>>(Q, Kbf, VT, A01, jmt, cKb, ATT);
    out_gemm<<<dim3(12, 32), 256, 0, stream>>>(ATT, We, be, out);
}

// Round 7
// 619.590 us; speedup vs baseline: 4.6158x; 1.6944x over previous
//
#include <hip/hip_runtime.h>
#include <hip/hip_bf16.h>
#include <math.h>

// Problem constants
#define BB 2
#define SQ 2048
#define NH 8
#define DKH 64
#define DVH 192
#define CIN 1536    // NH*DVH
#define KPD 512     // NH*DKH

typedef unsigned short u16t;
typedef short bf16x8 __attribute__((ext_vector_type(8)));
typedef float f32x4 __attribute__((ext_vector_type(4)));
typedef __attribute__((address_space(3))) unsigned char lds_u8;
typedef const __attribute__((address_space(1))) unsigned char glb_u8;

__device__ __forceinline__ u16t f2bf(float f) {
    unsigned int x = __float_as_uint(f);
    unsigned int r = x + 0x7FFF + ((x >> 16) & 1);   // RNE
    return (u16t)(r >> 16);
}
__device__ __forceinline__ float bf2f(u16t u) {
    return __uint_as_float(((unsigned int)u) << 16);
}
__device__ __forceinline__ void gload16(const void* g, void* l) {
    __builtin_amdgcn_global_load_lds((glb_u8*)g, (lds_u8*)l, 16, 0, 0);
}

// ---------------------------------------------------------------------------
// Suffix sums of Wr
// ---------------------------------------------------------------------------
__global__ void suffix_kernel(const float* __restrict__ Wr,
                              float* __restrict__ SUF0, float* __restrict__ SUF1) {
    int o = blockIdx.x * 256 + threadIdx.x;
    if (o >= KPD) return;
    float s = 0.f;
    SUF0[96 * KPD + o] = 0.f;
    for (int j = 95; j >= 0; j--) { s += Wr[j * KPD + o]; SUF0[j * KPD + o] = s; }
    s = 0.f;
    SUF1[96 * KPD + o] = 0.f;
    for (int j = 95; j >= 0; j--) { s += Wr[(96 + j) * KPD + o]; SUF1[j * KPD + o] = s; }
}

// jmt[dist] = #{j : cw[j] <= dist}
__global__ void jmt_kernel(unsigned char* __restrict__ jmt) {
    int tid = threadIdx.x;
    __shared__ float cwv[96];
    double pr_d = exp(log((double)(SQ + 1)) / 96.0);
    if (tid < 96) cwv[tid] = (float)(pow(pr_d, (double)(tid + 1)) - 1.0);
    __syncthreads();
    for (int dist = tid; dist < SQ; dist += 256) {
        float ad = (float)dist;
        int jm = 0;
        for (int j = 0; j < 96; j++) jm += (cwv[j] <= ad) ? 1 : 0;
        jmt[dist] = (unsigned char)jm;
    }
}

// ---------------------------------------------------------------------------
// x -> bf16 hi/lo (elementwise)
// ---------------------------------------------------------------------------
__global__ void conv_x(const float* __restrict__ x, u16t* __restrict__ xhi,
                       u16t* __restrict__ xlo) {
    size_t i = ((size_t)blockIdx.x * 256 + threadIdx.x) * 8;
    float4 a = *(const float4*)(x + i), b4 = *(const float4*)(x + i + 4);
    float v[8] = {a.x, a.y, a.z, a.w, b4.x, b4.y, b4.z, b4.w};
    u16t hi[8], lo[8];
#pragma unroll
    for (int j = 0; j < 8; j++) {
        hi[j] = f2bf(v[j]);
        lo[j] = f2bf(v[j] - bf2f(hi[j]));
    }
    ushort4 h0 = {hi[0], hi[1], hi[2], hi[3]}, h1 = {hi[4], hi[5], hi[6], hi[7]};
    ushort4 l0 = {lo[0], lo[1], lo[2], lo[3]}, l1 = {lo[4], lo[5], lo[6], lo[7]};
    *(ushort4*)&xhi[i] = h0; *(ushort4*)&xhi[i + 4] = h1;
    *(ushort4*)&xlo[i] = l0; *(ushort4*)&xlo[i + 4] = l1;
}

// ---------------------------------------------------------------------------
// Weight transpose + bf16 hi/lo convert: src[K=1536][N] -> dst[N][1536]
// ---------------------------------------------------------------------------
__global__ __launch_bounds__(256) void tconv(
    const float* __restrict__ src, u16t* __restrict__ dhi, u16t* __restrict__ dlo, int N) {
    __shared__ float tile[64][65];
    const int k0 = blockIdx.y * 64, n0 = blockIdx.x * 64;
    const int t = threadIdx.x;
    const int lr = t >> 4, lc4 = (t & 15) * 4;
#pragma unroll
    for (int rep = 0; rep < 4; rep++) {
        int row = rep * 16 + lr;
        *(float4*)&tile[row][lc4] = *(const float4*)(src + (size_t)(k0 + row) * N + n0 + lc4);
    }
    __syncthreads();
    const int nl = t >> 2, ks = t & 3;
    u16t hi[16], lo[16];
#pragma unroll
    for (int j = 0; j < 16; j++) {
        float v = tile[ks * 16 + j][nl];
        hi[j] = f2bf(v); lo[j] = f2bf(v - bf2f(hi[j]));
    }
    size_t off = (size_t)(n0 + nl) * CIN + k0 + ks * 16;
#pragma unroll
    for (int j = 0; j < 4; j++) {
        ushort4 h = {hi[4 * j], hi[4 * j + 1], hi[4 * j + 2], hi[4 * j + 3]};
        ushort4 lo4 = {lo[4 * j], lo[4 * j + 1], lo[4 * j + 2], lo[4 * j + 3]};
        *(ushort4*)&dhi[off + 4 * j] = h;
        *(ushort4*)&dlo[off + 4 * j] = lo4;
    }
}

// ---------------------------------------------------------------------------
// A01[b,h,q][j] = pack(bf16((q_s+rrb).suf1[j]), bf16((q_s+rrb).suf0[j]))
// ---------------------------------------------------------------------------
__global__ __launch_bounds__(256) void a01_kernel(
    const float* __restrict__ Q, const float* __restrict__ SUF0,
    const float* __restrict__ SUF1, const float* __restrict__ rrb,
    unsigned int* __restrict__ A01) {
    __shared__ float s0[97][65];
    __shared__ float s1[97][65];
    __shared__ float qs[32][65];
    int h = blockIdx.y, b = blockIdx.z, qb = blockIdx.x * 32;
    int tid = threadIdx.x;
    for (int idx = tid; idx < 97 * 64; idx += 256) {
        int j = idx >> 6, e = idx & 63;
        s0[j][e] = SUF0[j * KPD + h * 64 + e];
        s1[j][e] = SUF1[j * KPD + h * 64 + e];
    }
    for (int idx = tid; idx < 32 * 64; idx += 256) {
        int q = idx >> 6, e = idx & 63;
        qs[q][e] = Q[((size_t)(b * SQ + qb + q)) * KPD + h * 64 + e] + rrb[h * 64 + e];
    }
    __syncthreads();
    int q = tid >> 3, part = tid & 7;
    for (int j = part; j < 97; j += 8) {
        float d0 = 0.f, d1 = 0.f;
        for (int e = 0; e < 64; e++) {
            float qv = qs[q][e];
            d0 += qv * s0[j][e];
            d1 += qv * s1[j][e];
        }
        unsigned int pk = ((unsigned int)f2bf(d1) << 16) | (unsigned int)f2bf(d0);
        A01[(((size_t)(b * NH + h)) * SQ + qb + q) * 97 + j] = pk;
    }
}

// ---------------------------------------------------------------------------
// 3-term hi/lo MFMA GEMM core. A[.][1536] bf16 hi/lo (row-major, pre-offset by
// m0), BT[.][1536] bf16 hi/lo (pre-offset by n0). 128x128 tile, BK=32, 4 waves
// as 2x2, each wave 4x4 fragments of 16x16. LDS linear (64B rows: the frag
// read pattern lands 8 lanes/bank-quad = conflict-free, no swizzle needed).
// ---------------------------------------------------------------------------
__device__ __forceinline__ void gemm3_core(
    const u16t* __restrict__ Ahi, const u16t* __restrict__ Alo,
    const u16t* __restrict__ Bhi, const u16t* __restrict__ Blo,
    u16t* lds, f32x4 (&acc)[4][4]) {
    const int tid = threadIdx.x;
    const int w = tid >> 6, l = tid & 63;
    const int lan15 = l & 15, grp = l >> 4;
    const int wr = w >> 1, wc = w & 1;

#pragma unroll
    for (int a = 0; a < 4; a++)
#pragma unroll
        for (int bq = 0; bq < 4; bq++) acc[a][bq] = (f32x4){0.f, 0.f, 0.f, 0.f};

    // wave w stages one 8KB buffer: 0=A_hi, 1=A_lo, 2=B_hi, 3=B_lo
    const u16t* gsrc = (w == 0) ? Ahi : (w == 1) ? Alo : (w == 2) ? Bhi : Blo;
    const int srow = l >> 2, sc = (l & 3) * 8;    // lane -> (row-in-16, k-chunk)
    u16t* lbase = lds + w * 4096;

    for (int kt = 0; kt < 48; kt++) {
        const int k0 = kt * 32;
#pragma unroll
        for (int j = 0; j < 8; j++) {
            int row = j * 16 + srow;
            gload16(gsrc + (size_t)row * CIN + k0 + sc, lbase + j * 512);
        }
        __syncthreads();
        bf16x8 ah[4], al[4], bh[4], bl[4];
#pragma unroll
        for (int mi = 0; mi < 4; mi++) {
            int row = wr * 64 + mi * 16 + lan15;
            ah[mi] = *(const bf16x8*)&lds[row * 32 + grp * 8];
            al[mi] = *(const bf16x8*)&lds[4096 + row * 32 + grp * 8];
        }
#pragma unroll
        for (int ni = 0; ni < 4; ni++) {
            int row = wc * 64 + ni * 16 + lan15;
            bh[ni] = *(const bf16x8*)&lds[8192 + row * 32 + grp * 8];
            bl[ni] = *(const bf16x8*)&lds[12288 + row * 32 + grp * 8];
        }
#pragma unroll
        for (int mi = 0; mi < 4; mi++)
#pragma unroll
            for (int ni = 0; ni < 4; ni++) {
                acc[mi][ni] = __builtin_amdgcn_mfma_f32_16x16x32_bf16(ah[mi], bh[ni], acc[mi][ni], 0, 0, 0);
                acc[mi][ni] = __builtin_amdgcn_mfma_f32_16x16x32_bf16(ah[mi], bl[ni], acc[mi][ni], 0, 0, 0);
                acc[mi][ni] = __builtin_amdgcn_mfma_f32_16x16x32_bf16(al[mi], bh[ni], acc[mi][ni], 0, 0, 0);
            }
        __syncthreads();
    }
}

// Fused QKV projection (MFMA). grid (20, 32): n-space = Q(512)|K(512)|V(1536).
__global__ __launch_bounds__(256) void qkv_gemm3(
    const u16t* __restrict__ XAhi, const u16t* __restrict__ XAlo,
    const u16t* __restrict__ Whi, const u16t* __restrict__ Wlo,
    float* __restrict__ Q, u16t* __restrict__ Kbf, u16t* __restrict__ VT) {
    __shared__ __align__(16) u16t lds[16384];
    const int n0 = blockIdx.x * 128, m0 = blockIdx.y * 128;
    f32x4 acc[4][4];
    gemm3_core(XAhi + (size_t)m0 * CIN, XAlo + (size_t)m0 * CIN,
               Whi + (size_t)n0 * CIN, Wlo + (size_t)n0 * CIN, lds, acc);
    const int tid = threadIdx.x, w = tid >> 6, l = tid & 63;
    const int lan15 = l & 15, grp = l >> 4, wr = w >> 1, wc = w & 1;
    if (n0 < 512) {
#pragma unroll
        for (int mi = 0; mi < 4; mi++)
#pragma unroll
            for (int ni = 0; ni < 4; ni++) {
                int gn = n0 + wc * 64 + ni * 16 + lan15;
                int gm0 = m0 + wr * 64 + mi * 16 + grp * 4;
#pragma unroll
                for (int i = 0; i < 4; i++)
                    Q[(size_t)(gm0 + i) * KPD + gn] = acc[mi][ni][i] * 0.125f;
            }
    } else if (n0 < 1024) {
#pragma unroll
        for (int mi = 0; mi < 4; mi++)
#pragma unroll
            for (int ni = 0; ni < 4; ni++) {
                int gn = n0 - 512 + wc * 64 + ni * 16 + lan15;
                int gm0 = m0 + wr * 64 + mi * 16 + grp * 4;
#pragma unroll
                for (int i = 0; i < 4; i++)
                    Kbf[(size_t)(gm0 + i) * KPD + gn] = f2bf(acc[mi][ni][i]);
            }
    } else {
#pragma unroll
        for (int mi = 0; mi < 4; mi++)
#pragma unroll
            for (int ni = 0; ni < 4; ni++) {
                int cv = n0 - 1024 + wc * 64 + ni * 16 + lan15;
                int hh = cv / 192, dv = cv - hh * 192;
                int gm0 = m0 + wr * 64 + mi * 16 + grp * 4;
                int bidx = gm0 >> 11, s = gm0 & 2047;
                ushort4 pk = {f2bf(acc[mi][ni][0]), f2bf(acc[mi][ni][1]),
                              f2bf(acc[mi][ni][2]), f2bf(acc[mi][ni][3])};
                *(ushort4*)&VT[((size_t)(bidx * NH + hh) * 192 + dv) * SQ + s] = pk;
            }
    }
}

// Output projection (MFMA): out = ATT @ We + be. grid (12, 32).
__global__ __launch_bounds__(256) void out_gemm3(
    const u16t* __restrict__ Ahi, const u16t* __restrict__ Alo,
    const u16t* __restrict__ Whi, const u16t* __restrict__ Wlo,
    const float* __restrict__ be, float* __restrict__ out) {
    __shared__ __align__(16) u16t lds[16384];
    const int n0 = blockIdx.x * 128, m0 = blockIdx.y * 128;
    f32x4 acc[4][4];
    gemm3_core(Ahi + (size_t)m0 * CIN, Alo + (size_t)m0 * CIN,
               Whi + (size_t)n0 * CIN, Wlo + (size_t)n0 * CIN, lds, acc);
    const int tid = threadIdx.x, w = tid >> 6, l = tid & 63;
    const int lan15 = l & 15, grp = l >> 4, wr = w >> 1, wc = w & 1;
#pragma unroll
    for (int mi = 0; mi < 4; mi++)
#pragma unroll
        for (int ni = 0; ni < 4; ni++) {
            int gn = n0 + wc * 64 + ni * 16 + lan15;
            int gm0 = m0 + wr * 64 + mi * 16 + grp * 4;
            float bev = be[gn];
#pragma unroll
            for (int i = 0; i < 4; i++)
                out[(size_t)(gm0 + i) * CIN + gn] = acc[mi][ni][i] + bev;
        }
}

// cK[(b*8+h)*2048 + k] = rwb[h,:] . K[b,k,h,:]
__global__ void ck_kernel(const u16t* __restrict__ Kbf, const float* __restrict__ rwb,
                          float* __restrict__ cK) {
    int g = blockIdx.x * 256 + threadIdx.x;  // < 32768
    int k = g & 2047, h = (g >> 11) & 7, b = g >> 14;
    const u16t* kp = Kbf + ((size_t)(b * SQ + k)) * KPD + h * 64;
    const float* wp = rwb + h * 64;
    float s = 0.f;
#pragma unroll
    for (int c = 0; c < 8; c++) {
        bf16x8 kv = *(const bf16x8*)(kp + c * 8);
#pragma unroll
        for (int j = 0; j < 8; j++) s += bf2f((u16t)kv[j]) * wp[c * 8 + j];
    }
    cK[g] = s;
}

// ---------------------------------------------------------------------------
// MFMA flash attention. grid (S/64, H, B), 4 waves; wave owns 16 q-rows.
// Epilogue writes ATT as bf16 hi/lo (feeds out_gemm3's split-precision A).
// ---------------------------------------------------------------------------
__global__ __launch_bounds__(256) void attn_mfma(
    const float* __restrict__ Q, const u16t* __restrict__ Kbf, const u16t* __restrict__ VT,
    const unsigned int* __restrict__ A01, const unsigned char* __restrict__ jmtg,
    const float* __restrict__ cKg, u16t* __restrict__ ATThi, u16t* __restrict__ ATTlo) {
    __shared__ __align__(16) u16t k_s[32 * 72];
    __shared__ __align__(16) u16t vt_s[192 * 40];
    __shared__ __align__(16) u16t p_s[4][16 * 40];
    __shared__ unsigned int a01_s[64 * 97];
    __shared__ unsigned char jmt_s[2048];
    __shared__ float ck_s[32];

    const int q0blk = blockIdx.x * 64;
    const int h = blockIdx.y, b = blockIdx.z;
    const int tid = threadIdx.x;
    const int w = tid >> 6, l = tid & 63;
    const int lan15 = l & 15, grp = l >> 4;

    ((uint2*)jmt_s)[tid] = ((const uint2*)jmtg)[tid];
    {
        const unsigned int* a01g = A01 + (((size_t)(b * NH + h)) * SQ + q0blk) * 97;
        for (int idx = tid; idx < 64 * 97; idx += 256) a01_s[idx] = a01g[idx];
    }

    const int qrow = q0blk + w * 16 + lan15;
    bf16x8 qfrag[2];
#pragma unroll
    for (int g = 0; g < 2; g++) {
        const float* qp = Q + ((size_t)(b * SQ + qrow)) * KPD + h * 64 + g * 32 + grp * 8;
        float4 qa = *(const float4*)qp, qb4 = *(const float4*)(qp + 4);
        bf16x8 f;
        f[0] = (short)f2bf(qa.x); f[1] = (short)f2bf(qa.y);
        f[2] = (short)f2bf(qa.z); f[3] = (short)f2bf(qa.w);
        f[4] = (short)f2bf(qb4.x); f[5] = (short)f2bf(qb4.y);
        f[6] = (short)f2bf(qb4.z); f[7] = (short)f2bf(qb4.w);
        qfrag[g] = f;
    }

    f32x4 o_acc[12];
#pragma unroll
    for (int c = 0; c < 12; c++) o_acc[c] = (f32x4){0.f, 0.f, 0.f, 0.f};
    float m_run[4] = {-INFINITY, -INFINITY, -INFINITY, -INFINITY};
    float l_run[4] = {0.f, 0.f, 0.f, 0.f};

    const u16t* Kbase = Kbf + ((size_t)b * SQ) * KPD + h * 64;
    const u16t* Vbase = VT + ((size_t)(b * NH + h)) * 192 * SQ;
    const float* cKb = cKg + (size_t)(b * NH + h) * SQ;
    u16t* p_ws = p_s[w];

    for (int kt = 0; kt < SQ / 32; kt++) {
        const int k0 = kt * 32;
        {
            int row = tid >> 3, g = tid & 7;
            *(bf16x8*)&k_s[row * 72 + g * 8] =
                *(const bf16x8*)(Kbase + (size_t)(k0 + row) * KPD + g * 8);
        }
#pragma unroll
        for (int rep = 0; rep < 3; rep++) {
            int c = tid + rep * 256;
            int dv = c >> 2, g = c & 3;
            *(bf16x8*)&vt_s[dv * 40 + g * 8] =
                *(const bf16x8*)(Vbase + (size_t)dv * SQ + k0 + g * 8);
        }
        if (tid < 32) ck_s[tid] = cKb[k0 + tid];
        __syncthreads();

        f32x4 sacc[2];
#pragma unroll
        for (int ct = 0; ct < 2; ct++) {
            int krow = 16 * ct + lan15;
            bf16x8 kf0 = *(bf16x8*)&k_s[krow * 72 + grp * 8];
            bf16x8 kf1 = *(bf16x8*)&k_s[krow * 72 + 32 + grp * 8];
            f32x4 z = (f32x4){0.f, 0.f, 0.f, 0.f};
            z = __builtin_amdgcn_mfma_f32_16x16x32_bf16(qfrag[0], kf0, z, 0, 0, 0);
            z = __builtin_amdgcn_mfma_f32_16x16x32_bf16(qfrag[1], kf1, z, 0, 0, 0);
            sacc[ct] = z;
        }
        float ckv[2] = {ck_s[lan15], ck_s[16 + lan15]};

#pragma unroll
        for (int i = 0; i < 4; i++) {
            const int qg = q0blk + w * 16 + grp * 4 + i;
            float sv[2];
#pragma unroll
            for (int ct = 0; ct < 2; ct++) {
                int kg = k0 + 16 * ct + lan15;
                int dg = kg - qg;
                int dist = dg < 0 ? -dg : dg;
                int jm = (int)jmt_s[dist];
                unsigned int pk = a01_s[(w * 16 + grp * 4 + i) * 97 + jm];
                float a0 = bf2f((u16t)(pk & 0xFFFF));
                float a1 = bf2f((u16t)(pk >> 16));
                float sgn = (dg > 0) ? 1.f : (dg < 0 ? -1.f : 0.f);
                sv[ct] = sacc[ct][i] + a0 + sgn * a1 + ckv[ct];
            }
            float mx = fmaxf(sv[0], sv[1]);
            mx = fmaxf(mx, __shfl_xor(mx, 1));
            mx = fmaxf(mx, __shfl_xor(mx, 2));
            mx = fmaxf(mx, __shfl_xor(mx, 4));
            mx = fmaxf(mx, __shfl_xor(mx, 8));
            float mn = fmaxf(m_run[i], mx);
            float scl = __expf(m_run[i] - mn);
            float p0 = __expf(sv[0] - mn), p1 = __expf(sv[1] - mn);
            float ls = p0 + p1;
            ls += __shfl_xor(ls, 1);
            ls += __shfl_xor(ls, 2);
            ls += __shfl_xor(ls, 4);
            ls += __shfl_xor(ls, 8);
            l_run[i] = l_run[i] * scl + ls;
            m_run[i] = mn;
#pragma unroll
            for (int c = 0; c < 12; c++) o_acc[c][i] *= scl;
            p_ws[(grp * 4 + i) * 40 + lan15]      = f2bf(p0);
            p_ws[(grp * 4 + i) * 40 + 16 + lan15] = f2bf(p1);
        }

        bf16x8 pa = *(bf16x8*)&p_ws[lan15 * 40 + grp * 8];
#pragma unroll
        for (int c = 0; c < 12; c++) {
            bf16x8 vf = *(bf16x8*)&vt_s[(16 * c + lan15) * 40 + grp * 8];
            o_acc[c] = __builtin_amdgcn_mfma_f32_16x16x32_bf16(pa, vf, o_acc[c], 0, 0, 0);
        }
        __syncthreads();
    }

    float inv[4];
#pragma unroll
    for (int i = 0; i < 4; i++) inv[i] = 1.f / l_run[i];
#pragma unroll
    for (int c = 0; c < 12; c++)
#pragma unroll
        for (int i = 0; i < 4; i++) {
            int qg = q0blk + w * 16 + grp * 4 + i;
            size_t idx = ((size_t)(b * SQ + qg)) * CIN + h * 192 + 16 * c + lan15;
            float o = o_acc[c][i] * inv[i];
            u16t hv = f2bf(o);
            ATThi[idx] = hv;
            ATTlo[idx] = f2bf(o - bf2f(hv));
        }
}

// ---------------------------------------------------------------------------
extern "C" void kernel_launch(void* const* d_in, const int* in_sizes, int n_in,
                              void* d_out, int out_size, void* d_ws, size_t ws_size,
                              hipStream_t stream) {
    const float* x   = (const float*)d_in[0];
    const float* Wq  = (const float*)d_in[1];
    const float* Wk  = (const float*)d_in[2];
    const float* Wv  = (const float*)d_in[3];
    const float* Wr  = (const float*)d_in[4];
    const float* rwb = (const float*)d_in[5];
    const float* rrb = (const float*)d_in[6];
    const float* We  = (const float*)d_in[7];
    const float* be  = (const float*)d_in[8];
    float* out = (float*)d_out;

    float* ws = (float*)d_ws;
    // layout (f32-word offsets). Aliases:
    //  - A01 overlays WTh/WTl (dead after qkv_gemm3; a01 runs after it)
    //  - WeTh/WeTl overlay Q+Kbf (dead after attn_mfma; their tconv runs after it)
    //  - XAhi/XAlo become ATThi/ATTlo (x dead after qkv_gemm3)
    float* Q     = ws;                                  // 2,097,152 w
    u16t*  Kbf   = (u16t*)(ws + 2097152);               // 1,048,576 w
    u16t*  VT    = (u16t*)(ws + 3145728);               // 3,145,728 w
    u16t*  XAhi  = (u16t*)(ws + 6291456);               // 3,145,728 w
    u16t*  XAlo  = (u16t*)(ws + 9437184);               // 3,145,728 w
    u16t*  WTh   = (u16t*)(ws + 12582912);              // 1,966,080 w
    u16t*  WTl   = (u16t*)(ws + 14548992);              // 1,966,080 w
    float* SUF0  = ws + 16515072;                       // 49,664 w
    float* SUF1  = ws + 16564736;                       // 49,664 w
    float* cKb   = ws + 16614400;                       // 32,768 w
    unsigned char* jmt = (unsigned char*)(ws + 16647168);  // 2048 B
    unsigned int* A01  = (unsigned int*)(ws + 12582912);   // 3,178,496 u32 (fits WT's 3,932,160 w)
    u16t*  WeTh  = (u16t*)(ws);                            // 1,179,648 w
    u16t*  WeTl  = (u16t*)(ws + 1179648);                  // ends 2,359,296 w (< Q+Kbf 3,145,728)
    // total 16,647,680 words = 66.6 MB (63.5 MiB)

    suffix_kernel<<<2, 256, 0, stream>>>(Wr, SUF0, SUF1);
    jmt_kernel<<<1, 256, 0, stream>>>(jmt);
    conv_x<<<3072, 256, 0, stream>>>(x, XAhi, XAlo);
    tconv<<<dim3(8, 24), 256, 0, stream>>>(Wq, WTh, WTl, KPD);
    tconv<<<dim3(8, 24), 256, 0, stream>>>(Wk, WTh + (size_t)512 * CIN, WTl + (size_t)512 * CIN, KPD);
    tconv<<<dim3(24, 24), 256, 0, stream>>>(Wv, WTh + (size_t)1024 * CIN, WTl + (size_t)1024 * CIN, CIN);
    qkv_gemm3<<<dim3(20, 32), 256, 0, stream>>>(XAhi, XAlo, WTh, WTl, Q, Kbf, VT);
    ck_kernel<<<128, 256, 0, stream>>>(Kbf, rwb, cKb);
    a01_kernel<<<dim3(64, NH, BB), 256, 0, stream>>>(Q, SUF0, SUF1, rrb, A01);
    attn_mfma<<<dim3(SQ / 64, NH, BB), 256, 0, stream>>>(Q, Kbf, VT, A01, jmt, cKb, XAhi, XAlo);
    tconv<<<dim3(24, 24), 256, 0, stream>>>(We, WeTh, WeTl, CIN);
    out_gemm3<<<dim3(12, 32), 256, 0, stream>>>(XAhi, XAlo, WeTh, WeTl, be, out);
}